// Round 2
// 164.686 us; speedup vs baseline: 1.0324x; 1.0324x over previous
//
#include <hip/hip_runtime.h>
#include <math.h>

#define NROWS   16384
#define IN_DIM  64
#define HID     256
#define OUT_DIM 64
#define NEXP    256
#define MT      112    // rows per tile (7 x 16); covers ~all experts in one pass
#define NT      7      // row tiles of 16
#define HP      264    // padded LDS row stride (bf16 elems): 528 B, 16B-aligned

typedef __attribute__((ext_vector_type(8))) short short8;   // 8 bf16 (4 VGPRs)
typedef __attribute__((ext_vector_type(4))) float f32x4;
typedef __attribute__((ext_vector_type(4))) unsigned uint4v;
typedef __attribute__((ext_vector_type(2))) unsigned uint2v;

// ---------------- parallel bucketing: memset + 3 small kernels ----------------

__global__ __launch_bounds__(256) void hist_k(const int* __restrict__ ind,
                                              int* __restrict__ hist) {
  int n = blockIdx.x * 256 + threadIdx.x;
  atomicAdd(&hist[ind[n]], 1);
}

__global__ __launch_bounds__(256) void scan_k(const int* __restrict__ hist,
                                              int* __restrict__ offsets,
                                              int* __restrict__ cur) {
  __shared__ int s[NEXP];
  int t = threadIdx.x;
  int h = hist[t];            // all reads complete before any write to cur/offsets
  s[t] = h;
  __syncthreads();
  for (int d = 1; d < NEXP; d <<= 1) {
    int v = (t >= d) ? s[t - d] : 0;
    __syncthreads();
    s[t] += v;
    __syncthreads();
  }
  int exc = s[t] - h;
  offsets[t] = exc;
  cur[t] = exc;
  if (t == NEXP - 1) offsets[NEXP] = s[t];
}

__global__ __launch_bounds__(256) void scatter_k(const int* __restrict__ ind,
                                                 int* __restrict__ cur,
                                                 int* __restrict__ rows) {
  int n = blockIdx.x * 256 + threadIdx.x;
  int p = atomicAdd(&cur[ind[n]], 1);
  rows[p] = n;
}

// ---------------- helpers ----------------

__device__ __forceinline__ unsigned bf16_rn(float f) {
  unsigned u = __builtin_bit_cast(unsigned, f);
  unsigned r = 0x7fffu + ((u >> 16) & 1u);
  return (u + r) >> 16;
}

__device__ __forceinline__ unsigned pk2(float a, float b) {
  return bf16_rn(a) | (bf16_rn(b) << 16);
}

__device__ __forceinline__ short8 cvt8(f32x4 w0, f32x4 w1) {
  uint4v u;
  u.x = pk2(w0.x, w0.y);
  u.y = pk2(w0.z, w0.w);
  u.z = pk2(w1.x, w1.y);
  u.w = pk2(w1.z, w1.w);
  return __builtin_bit_cast(short8, u);
}

__device__ __forceinline__ float fast_tanh(float v) {
  float e = __expf(2.f * v);
  return 1.f - 2.f * __builtin_amdgcn_rcpf(e + 1.f);
}

// Async-DMA one 32 KB fp32 weight slice into LDS (linear dest, per-lane src).
// Logical slice layout [R][C] floats with C*4/16 = (1<<CPRL) 16B-chunks per row.
// 512 threads x 4 chunks = 2048 chunks = 32768 B.
template <int CPRL>
__device__ __forceinline__ void stage_slice(const float* __restrict__ g, int krow,
                                            int colbase, float* l, int t) {
#pragma unroll
  for (int r = 0; r < 4; r++) {
    int c = r * 512 + t;                       // chunk id 0..2047
    int row = c >> CPRL;
    int cin = c & ((1 << CPRL) - 1);
    const float* src = g + (size_t)row * krow + colbase + cin * 4;
    __builtin_amdgcn_global_load_lds(
        (const __attribute__((address_space(1))) void*)src,
        (__attribute__((address_space(3))) void*)(l + (size_t)c * 4), 16, 0, 0);
  }
}

// One 32-K slice of a 256-neuron layer: A = staged LDS fp32 [256][32],
// B = H rows (bf16), acc[mt][nt] over this wave's 32 neurons x 112 rows.
__device__ __forceinline__ void slice_mm(const float* Ws, const unsigned short* Hin,
                                         int hofs, int w, int l15, int q,
                                         f32x4 (&acc)[2][NT]) {
  short8 a[2];
#pragma unroll
  for (int mt = 0; mt < 2; mt++) {
    const float* ap = Ws + (w * 32 + mt * 16 + l15) * 32 + q * 8;
    a[mt] = cvt8(*(const f32x4*)ap, *(const f32x4*)(ap + 4));
  }
#pragma unroll
  for (int nt = 0; nt < NT; nt++) {
    short8 b = *(const short8*)&Hin[(nt * 16 + l15) * HP + hofs + q * 8];
#pragma unroll
    for (int mt = 0; mt < 2; mt++)
      acc[mt][nt] =
          __builtin_amdgcn_mfma_f32_16x16x32_bf16(a[mt], b, acc[mt][nt], 0, 0, 0);
  }
}

// One 128-K slice of the 64-neuron output layer: A = staged LDS fp32 [64][128].
// Wave w owns neurons (w&3)*16..+15; waves 0-3 cover row tiles 0..3, waves 4-7
// cover row tiles 4..6 (tile 7 does not exist at MT=112).
__device__ __forceinline__ void slice_l3(const float* Ws, const unsigned short* Hin,
                                         int ks2, int w, int l15, int q,
                                         f32x4 (&accl)[4]) {
#pragma unroll
  for (int kk = 0; kk < 4; kk++) {
    const float* ap = Ws + ((w & 3) * 16 + l15) * 128 + kk * 32 + q * 8;
    short8 a = cvt8(*(const f32x4*)ap, *(const f32x4*)(ap + 4));
    int hofs = ks2 * 128 + kk * 32;
#pragma unroll
    for (int i = 0; i < 4; i++) {
      int nt = (w >> 2) * 4 + i;
      if (nt < NT) {
        short8 b = *(const short8*)&Hin[(nt * 16 + l15) * HP + hofs + q * 8];
        accl[i] = __builtin_amdgcn_mfma_f32_16x16x32_bf16(a, b, accl[i], 0, 0, 0);
      }
    }
  }
}

// tanh + pack + store h frags: frag (mt,nt) -> H[row nt*16+l15][neurons w*32+mt*16+q*4..+3]
__device__ __forceinline__ void write_h8(f32x4 (&acc)[2][NT], unsigned short* Hd,
                                         int w, int l15, int q) {
#pragma unroll
  for (int mt = 0; mt < 2; mt++)
#pragma unroll
    for (int nt = 0; nt < NT; nt++) {
      uint2v v;
      v.x = pk2(fast_tanh(acc[mt][nt].x), fast_tanh(acc[mt][nt].y));
      v.y = pk2(fast_tanh(acc[mt][nt].z), fast_tanh(acc[mt][nt].w));
      *(uint2v*)&Hd[(nt * 16 + l15) * HP + w * 32 + mt * 16 + q * 4] = v;
    }
}

// ---------------- main MLP kernel: 1 block per expert, streamed weights -------
// LDS: H 59136 B + Wb 65536 B = 124672 B  (<= 128 KiB proven envelope)

__global__ __launch_bounds__(512, 2) void mlp_k(
    const float* __restrict__ x,
    const float* __restrict__ W1, const float* __restrict__ b1,
    const float* __restrict__ W2, const float* __restrict__ b2,
    const float* __restrict__ Wl, const float* __restrict__ bl,
    const int* __restrict__ rows, const int* __restrict__ offsets,
    float* __restrict__ out) {
  __shared__ __align__(16) unsigned short H[MT * HP];  // 59136 B
  __shared__ __align__(16) float Wb[2][8192];          // 65536 B dbuf staging

  const int t = threadIdx.x;
  const int w = t >> 6;          // wave 0..7
  const int l15 = t & 15;
  const int q = (t >> 4) & 3;
  const int e = blockIdx.x;
  const int beg = offsets[e];
  const int cnt = offsets[e + 1] - beg;

  const float* W1e = W1 + (size_t)e * HID * IN_DIM;
  const float* W2e = W2 + (size_t)e * HID * HID;
  const float* Wle = Wl + (size_t)e * OUT_DIM * HID;

  f32x4 b1v[2], b2v[2], blv;
#pragma unroll
  for (int mt = 0; mt < 2; mt++) {
    b1v[mt] = *(const f32x4*)(b1 + (size_t)e * HID + w * 32 + mt * 16 + q * 4);
    b2v[mt] = *(const f32x4*)(b2 + (size_t)e * HID + w * 32 + mt * 16 + q * 4);
  }
  blv = *(const f32x4*)(bl + (size_t)e * OUT_DIM + (w & 3) * 16 + q * 4);

  const int sr = t >> 2;          // x-stage: row 0..127 (only 0..111 active)
  const int sc = (t & 3) * 16;    // x-stage: col base

  for (int mt0 = 0; mt0 < cnt; mt0 += MT) {
    // slice 0 = W1 ks0 in flight while we stage x
    stage_slice<3>(W1e, IN_DIM, 0, Wb[0], t);
    if (sr < MT) {
      int gm = mt0 + sr;
      bool val = gm < cnt;
      int r = val ? rows[beg + gm] : 0;
      const float* xr = x + (size_t)r * IN_DIM + sc;
      uint4v u0, u1;
      if (val) {
        f32x4 a0 = *(const f32x4*)(xr);
        f32x4 a1 = *(const f32x4*)(xr + 4);
        f32x4 a2 = *(const f32x4*)(xr + 8);
        f32x4 a3 = *(const f32x4*)(xr + 12);
        u0.x = pk2(a0.x, a0.y); u0.y = pk2(a0.z, a0.w);
        u0.z = pk2(a1.x, a1.y); u0.w = pk2(a1.z, a1.w);
        u1.x = pk2(a2.x, a2.y); u1.y = pk2(a2.z, a2.w);
        u1.z = pk2(a3.x, a3.y); u1.w = pk2(a3.z, a3.w);
      } else {
        u0 = (uint4v){0, 0, 0, 0};
        u1 = (uint4v){0, 0, 0, 0};
      }
      *(uint4v*)&H[sr * HP + sc] = u0;
      *(uint4v*)&H[sr * HP + sc + 8] = u1;
    }
    __syncthreads();  // x staged + slice0 landed (barrier drains vmcnt)

    // ---- layer1: x(K=64) -> h1(256), tanh. Slices 0..1.
    f32x4 acc[2][NT];
#pragma unroll
    for (int mt = 0; mt < 2; mt++)
#pragma unroll
      for (int nt = 0; nt < NT; nt++) acc[mt][nt] = b1v[mt];

    stage_slice<3>(W1e, IN_DIM, 32, Wb[1], t);   // slice1 = W1 ks1
    slice_mm(Wb[0], H, 0, w, l15, q, acc);
    __syncthreads();

    stage_slice<3>(W2e, HID, 0, Wb[0], t);       // slice2 = W2 ks0
    slice_mm(Wb[1], H, 32, w, l15, q, acc);
    __syncthreads();

    write_h8(acc, H, w, l15, q);                 // h1 (in place over x)
    __syncthreads();

    // ---- layer2: h1(K=256) -> h2(256), tanh. Slices 2..9.
#pragma unroll
    for (int mt = 0; mt < 2; mt++)
#pragma unroll
      for (int nt = 0; nt < NT; nt++) acc[mt][nt] = b2v[mt];

    for (int ks = 0; ks < 8; ks++) {
      if (ks < 7) stage_slice<3>(W2e, HID, (ks + 1) * 32, Wb[(ks + 1) & 1], t);
      else        stage_slice<5>(Wle, HID, 0, Wb[0], t);   // slice10 = Wl cols 0..127
      slice_mm(Wb[ks & 1], H, ks * 32, w, l15, q, acc);
      __syncthreads();
    }

    write_h8(acc, H, w, l15, q);                 // h2 (in place over h1)
    __syncthreads();

    // ---- layer3: h2(K=256) -> out(64). Slices 10..11.
    f32x4 accl[4];
#pragma unroll
    for (int i = 0; i < 4; i++) accl[i] = blv;

    stage_slice<5>(Wle, HID, 128, Wb[1], t);     // slice11 = Wl cols 128..255
    slice_l3(Wb[0], H, 0, w, l15, q, accl);
    __syncthreads();
    slice_l3(Wb[1], H, 1, w, l15, q, accl);

#pragma unroll
    for (int i = 0; i < 4; i++) {
      int nt = (w >> 2) * 4 + i;
      if (nt < NT) {
        int gm = mt0 + nt * 16 + l15;
        if (gm < cnt) {
          int r = rows[beg + gm];
          *(f32x4*)(out + (size_t)r * OUT_DIM + (w & 3) * 16 + q * 4) = accl[i];
        }
      }
    }
    __syncthreads();  // protect H/Wb before next tile's staging (multi-tile case)
  }
}

// ---------------- launcher ----------------

extern "C" void kernel_launch(void* const* d_in, const int* in_sizes, int n_in,
                              void* d_out, int out_size, void* d_ws, size_t ws_size,
                              hipStream_t stream) {
  const float* x   = (const float*)d_in[0];
  const int*   ind = (const int*)d_in[1];
  const float* W1  = (const float*)d_in[2];
  const float* b1  = (const float*)d_in[3];
  const float* W2  = (const float*)d_in[4];
  const float* b2  = (const float*)d_in[5];
  const float* Wl  = (const float*)d_in[6];
  const float* bl  = (const float*)d_in[7];
  float* out = (float*)d_out;

  // ws layout (ints): offsets @0 (257) | hist/cur @260 (256) | rows @516 (16384)
  // hist and cur alias: scan_k reads all of hist before writing any of cur.
  int* offsets = (int*)d_ws;
  int* cur     = (int*)d_ws + 260;
  int* hist    = (int*)d_ws + 260;
  int* rows    = (int*)d_ws + 516;

  hipMemsetAsync(hist, 0, NEXP * sizeof(int), stream);
  hist_k<<<NROWS / 256, 256, 0, stream>>>(ind, hist);
  scan_k<<<1, 256, 0, stream>>>(hist, offsets, cur);
  scatter_k<<<NROWS / 256, 256, 0, stream>>>(ind, cur, rows);
  mlp_k<<<NEXP, 512, 0, stream>>>(x, W1, b1, W2, b2, Wl, bl, rows, offsets, out);
}

// Round 3
// 164.410 us; speedup vs baseline: 1.0341x; 1.0017x over previous
//
#include <hip/hip_runtime.h>
#include <math.h>

#define NROWS   16384
#define IN_DIM  64
#define HID     256
#define OUT_DIM 64
#define NEXP    256
#define MT      112    // rows per tile (7 x 16); covers ~all experts in one pass
#define NT      7      // row tiles of 16
#define HP      264    // padded LDS row stride (bf16 elems): 528 B, 16B-aligned

typedef __attribute__((ext_vector_type(8))) short short8;   // 8 bf16 (4 VGPRs)
typedef __attribute__((ext_vector_type(4))) float f32x4;
typedef __attribute__((ext_vector_type(4))) unsigned uint4v;
typedef __attribute__((ext_vector_type(2))) unsigned uint2v;

// counted-vmcnt barrier pair: publish own LDS writes, wait oldest DMAs, sync.
// vmcnt(4) = wait until <=4 vmem ops outstanding -> only the newest staged
// slice (4 global_load_lds) stays in flight across the barrier.
#define WAITVM4_BAR() do { \
    asm volatile("s_waitcnt vmcnt(4) lgkmcnt(0)" ::: "memory"); \
    __builtin_amdgcn_s_barrier(); } while (0)
#define WAITVM0_BAR() do { \
    asm volatile("s_waitcnt vmcnt(0) lgkmcnt(0)" ::: "memory"); \
    __builtin_amdgcn_s_barrier(); } while (0)
#define RBAR() __builtin_amdgcn_s_barrier()
#define MEMFENCE() asm volatile("" ::: "memory")

// ---------------- parallel bucketing: memset + 3 small kernels ----------------

__global__ __launch_bounds__(256) void hist_k(const int* __restrict__ ind,
                                              int* __restrict__ hist) {
  int n = blockIdx.x * 256 + threadIdx.x;
  atomicAdd(&hist[ind[n]], 1);
}

__global__ __launch_bounds__(256) void scan_k(const int* __restrict__ hist,
                                              int* __restrict__ offsets,
                                              int* __restrict__ cur) {
  __shared__ int s[NEXP];
  int t = threadIdx.x;
  int h = hist[t];            // all reads complete before any write to cur/offsets
  s[t] = h;
  __syncthreads();
  for (int d = 1; d < NEXP; d <<= 1) {
    int v = (t >= d) ? s[t - d] : 0;
    __syncthreads();
    s[t] += v;
    __syncthreads();
  }
  int exc = s[t] - h;
  offsets[t] = exc;
  cur[t] = exc;
  if (t == NEXP - 1) offsets[NEXP] = s[t];
}

__global__ __launch_bounds__(256) void scatter_k(const int* __restrict__ ind,
                                                 int* __restrict__ cur,
                                                 int* __restrict__ rows) {
  int n = blockIdx.x * 256 + threadIdx.x;
  int p = atomicAdd(&cur[ind[n]], 1);
  rows[p] = n;
}

// ---------------- helpers ----------------

__device__ __forceinline__ unsigned bf16_rn(float f) {
  unsigned u = __builtin_bit_cast(unsigned, f);
  unsigned r = 0x7fffu + ((u >> 16) & 1u);
  return (u + r) >> 16;
}

__device__ __forceinline__ unsigned pk2(float a, float b) {
  return bf16_rn(a) | (bf16_rn(b) << 16);
}

__device__ __forceinline__ short8 cvt8(f32x4 w0, f32x4 w1) {
  uint4v u;
  u.x = pk2(w0.x, w0.y);
  u.y = pk2(w0.z, w0.w);
  u.z = pk2(w1.x, w1.y);
  u.w = pk2(w1.z, w1.w);
  return __builtin_bit_cast(short8, u);
}

__device__ __forceinline__ float fast_tanh(float v) {
  float e = __expf(2.f * v);
  return 1.f - 2.f * __builtin_amdgcn_rcpf(e + 1.f);
}

// Async-DMA one 32 KB fp32 weight slice into LDS (linear dest, per-lane src).
// Slice layout [R][C] floats, (1<<CPRL) 16B-chunks per row. The SOURCE chunk
// is XOR-swizzled within its row (c ^= row&7) so that the bank-conflict-free
// swizzled layout lands in a LINEAR LDS destination (rule: swizzle both sides
// or neither; gload_lds dest must be base+lane*16).
// 512 threads x 4 chunks = 2048 chunks = 32768 B.
template <int CPRL>
__device__ __forceinline__ void stage_slice(const float* __restrict__ g, int krow,
                                            int colbase, float* l, int t) {
#pragma unroll
  for (int r = 0; r < 4; r++) {
    int c = r * 512 + t;                        // dest chunk id 0..2047 (linear)
    int cs = c ^ ((c >> CPRL) & 7);             // swizzled source chunk
    int row = cs >> CPRL;
    int cin = cs & ((1 << CPRL) - 1);
    const float* src = g + (size_t)row * krow + colbase + cin * 4;
    __builtin_amdgcn_global_load_lds(
        (const __attribute__((address_space(1))) void*)src,
        (__attribute__((address_space(3))) void*)(l + (size_t)c * 4), 16, 0, 0);
  }
}

// One 32-K slice of a 256-neuron layer: A = staged LDS fp32 [256][32] (swizzled),
// B = H rows (bf16), acc[mt][nt] over this wave's 32 neurons x 112 rows.
__device__ __forceinline__ void slice_mm(const float* Ws, const unsigned short* Hin,
                                         int hofs, int w, int l15, int q,
                                         f32x4 (&acc)[2][NT]) {
  const int xa = (l15 & 7) << 2;                // read-side swizzle (floats)
  const int c0 = (q * 8) ^ xa;
  const int c1 = (q * 8 + 4) ^ xa;
  short8 a[2];
#pragma unroll
  for (int mt = 0; mt < 2; mt++) {
    const float* ap = Ws + (w * 32 + mt * 16 + l15) * 32;
    a[mt] = cvt8(*(const f32x4*)(ap + c0), *(const f32x4*)(ap + c1));
  }
#pragma unroll
  for (int nt = 0; nt < NT; nt++) {
    short8 b = *(const short8*)&Hin[(nt * 16 + l15) * HP + hofs + q * 8];
#pragma unroll
    for (int mt = 0; mt < 2; mt++)
      acc[mt][nt] =
          __builtin_amdgcn_mfma_f32_16x16x32_bf16(a[mt], b, acc[mt][nt], 0, 0, 0);
  }
}

// One 128-K slice of the output layer: A = staged LDS fp32 [64][128] (swizzled).
// Wave w owns neurons (w&3)*16..+15; waves 0-3 cover row tiles 0..3, waves 4-7
// cover tiles 4..6 (tile 7 does not exist at MT=112).
__device__ __forceinline__ void slice_l3(const float* Ws, const unsigned short* Hin,
                                         int ks2, int w, int l15, int q,
                                         f32x4 (&accl)[4]) {
  const int xa = (l15 & 7) << 2;
  const int c0 = (q * 8) ^ xa;
  const int c1 = (q * 8 + 4) ^ xa;
#pragma unroll
  for (int kk = 0; kk < 4; kk++) {
    const float* ap = Ws + ((w & 3) * 16 + l15) * 128 + kk * 32;
    short8 a = cvt8(*(const f32x4*)(ap + c0), *(const f32x4*)(ap + c1));
    int hofs = ks2 * 128 + kk * 32;
#pragma unroll
    for (int i = 0; i < 4; i++) {
      int nt = (w >> 2) * 4 + i;
      if (nt < NT) {
        short8 b = *(const short8*)&Hin[(nt * 16 + l15) * HP + hofs + q * 8];
        accl[i] = __builtin_amdgcn_mfma_f32_16x16x32_bf16(a, b, accl[i], 0, 0, 0);
      }
    }
  }
}

// tanh + pack + store h frags: frag (mt,nt) -> H[row nt*16+l15][neurons w*32+mt*16+q*4..+3]
__device__ __forceinline__ void write_h8(f32x4 (&acc)[2][NT], unsigned short* Hd,
                                         int w, int l15, int q) {
#pragma unroll
  for (int mt = 0; mt < 2; mt++)
#pragma unroll
    for (int nt = 0; nt < NT; nt++) {
      uint2v v;
      v.x = pk2(fast_tanh(acc[mt][nt].x), fast_tanh(acc[mt][nt].y));
      v.y = pk2(fast_tanh(acc[mt][nt].z), fast_tanh(acc[mt][nt].w));
      *(uint2v*)&Hd[(nt * 16 + l15) * HP + w * 32 + mt * 16 + q * 4] = v;
    }
}

// ---------------- main MLP kernel: 1 block per expert, streamed weights -------
// LDS: H 59136 B + Wb 65536 B = 124672 B  (1 block/CU).
// Pipeline: 12 x 32KB slices, 2-buffer, counted vmcnt(4) so the next slice's
// DMA stays in flight across both per-slice barriers (no vmcnt(0) drain in
// the main loop -> steady 64 KB/CU outstanding).

__global__ __launch_bounds__(512, 2) void mlp_k(
    const float* __restrict__ x,
    const float* __restrict__ W1, const float* __restrict__ b1,
    const float* __restrict__ W2, const float* __restrict__ b2,
    const float* __restrict__ Wl, const float* __restrict__ bl,
    const int* __restrict__ rows, const int* __restrict__ offsets,
    float* __restrict__ out) {
  __shared__ __align__(16) unsigned short H[MT * HP];  // 59136 B
  __shared__ __align__(16) float Wb[2][8192];          // 65536 B dbuf staging

  const int t = threadIdx.x;
  const int w = t >> 6;          // wave 0..7
  const int l15 = t & 15;
  const int q = (t >> 4) & 3;
  const int e = blockIdx.x;
  const int beg = offsets[e];
  const int cnt = offsets[e + 1] - beg;

  const float* W1e = W1 + (size_t)e * HID * IN_DIM;
  const float* W2e = W2 + (size_t)e * HID * HID;
  const float* Wle = Wl + (size_t)e * OUT_DIM * HID;

  f32x4 b1v[2], b2v[2], blv;
#pragma unroll
  for (int mt = 0; mt < 2; mt++) {
    b1v[mt] = *(const f32x4*)(b1 + (size_t)e * HID + w * 32 + mt * 16 + q * 4);
    b2v[mt] = *(const f32x4*)(b2 + (size_t)e * HID + w * 32 + mt * 16 + q * 4);
  }
  blv = *(const f32x4*)(bl + (size_t)e * OUT_DIM + (w & 3) * 16 + q * 4);

  const int sr = t >> 2;          // x-stage: row 0..127 (only 0..111 active)
  const int sc = (t & 3) * 16;    // x-stage: col base

  for (int mt0 = 0; mt0 < cnt; mt0 += MT) {
    // ---- x-gather loads (reg path) issued first, so the compiler's wait for
    // them (before convert) can leave the weight DMAs below in flight.
    f32x4 a0, a1, a2, a3;
    bool val = false;
    if (sr < MT) {
      int gm = mt0 + sr;
      val = gm < cnt;
      int r = val ? rows[beg + gm] : 0;
      const float* xr = x + (size_t)r * IN_DIM + sc;
      if (val) {
        a0 = *(const f32x4*)(xr);
        a1 = *(const f32x4*)(xr + 4);
        a2 = *(const f32x4*)(xr + 8);
        a3 = *(const f32x4*)(xr + 12);
      }
    }
    MEMFENCE();
    stage_slice<3>(W1e, IN_DIM, 0, Wb[0], t);    // s0 = W1 ks0
    MEMFENCE();
    stage_slice<3>(W1e, IN_DIM, 32, Wb[1], t);   // s1 = W1 ks1
    MEMFENCE();
    if (sr < MT) {
      uint4v u0, u1;
      if (val) {
        u0.x = pk2(a0.x, a0.y); u0.y = pk2(a0.z, a0.w);
        u0.z = pk2(a1.x, a1.y); u0.w = pk2(a1.z, a1.w);
        u1.x = pk2(a2.x, a2.y); u1.y = pk2(a2.z, a2.w);
        u1.z = pk2(a3.x, a3.y); u1.w = pk2(a3.z, a3.w);
      } else {
        u0 = (uint4v){0, 0, 0, 0};
        u1 = (uint4v){0, 0, 0, 0};
      }
      *(uint4v*)&H[sr * HP + sc] = u0;
      *(uint4v*)&H[sr * HP + sc + 8] = u1;
    }

    // ---- layer1: x(K=64) -> h1(256), tanh. Slices s0,s1.
    f32x4 acc[2][NT];
#pragma unroll
    for (int mt = 0; mt < 2; mt++)
#pragma unroll
      for (int nt = 0; nt < NT; nt++) acc[mt][nt] = b1v[mt];

    WAITVM4_BAR();                               // x in H (all waves), s0 landed
    slice_mm(Wb[0], H, 0, w, l15, q, acc);
    RBAR();                                      // all waves done reading Wb0
    stage_slice<3>(W2e, HID, 0, Wb[0], t);       // s2 = W2 ks0

    WAITVM4_BAR();                               // s1 landed
    slice_mm(Wb[1], H, 32, w, l15, q, acc);
    RBAR();                                      // all waves done reading Wb1 + x
    stage_slice<3>(W2e, HID, 32, Wb[1], t);      // s3 = W2 ks1
    write_h8(acc, H, w, l15, q);                 // h1 (in place over x)

    // ---- layer2: h1(K=256) -> h2(256), tanh. Slices s2..s9.
#pragma unroll
    for (int mt = 0; mt < 2; mt++)
#pragma unroll
      for (int nt = 0; nt < NT; nt++) acc[mt][nt] = b2v[mt];

    for (int ks = 0; ks < 8; ks++) {
      WAITVM4_BAR();                             // slice s(2+ks) landed, h visible
      slice_mm(Wb[ks & 1], H, ks * 32, w, l15, q, acc);
      RBAR();                                    // buffer free to overwrite
      if (ks < 6) {
        stage_slice<3>(W2e, HID, (ks + 2) * 32, Wb[ks & 1], t);
      } else if (ks == 6) {
        stage_slice<5>(Wle, HID, 0, Wb[0], t);   // s10 = Wl cols 0..127
      } else {
        stage_slice<5>(Wle, HID, 128, Wb[1], t); // s11 = Wl cols 128..255
        write_h8(acc, H, w, l15, q);             // h2 (in place over h1)
      }
    }

    // ---- layer3: h2(K=256) -> out(64). Slices s10,s11.
    f32x4 accl[4];
#pragma unroll
    for (int i = 0; i < 4; i++) accl[i] = blv;

    WAITVM4_BAR();                               // s10 landed, h2 visible
    slice_l3(Wb[0], H, 0, w, l15, q, accl);
    WAITVM0_BAR();                               // s11 landed (last DMA)
    slice_l3(Wb[1], H, 1, w, l15, q, accl);

#pragma unroll
    for (int i = 0; i < 4; i++) {
      int nt = (w >> 2) * 4 + i;
      if (nt < NT) {
        int gm = mt0 + nt * 16 + l15;
        if (gm < cnt) {
          int r = rows[beg + gm];
          *(f32x4*)(out + (size_t)r * OUT_DIM + (w & 3) * 16 + q * 4) = accl[i];
        }
      }
    }
    RBAR();  // protect H/Wb before next tile's staging (multi-tile case)
  }
}

// ---------------- launcher ----------------

extern "C" void kernel_launch(void* const* d_in, const int* in_sizes, int n_in,
                              void* d_out, int out_size, void* d_ws, size_t ws_size,
                              hipStream_t stream) {
  const float* x   = (const float*)d_in[0];
  const int*   ind = (const int*)d_in[1];
  const float* W1  = (const float*)d_in[2];
  const float* b1  = (const float*)d_in[3];
  const float* W2  = (const float*)d_in[4];
  const float* b2  = (const float*)d_in[5];
  const float* Wl  = (const float*)d_in[6];
  const float* bl  = (const float*)d_in[7];
  float* out = (float*)d_out;

  // ws layout (ints): offsets @0 (257) | hist/cur @260 (256) | rows @516 (16384)
  // hist and cur alias: scan_k reads all of hist before writing any of cur.
  int* offsets = (int*)d_ws;
  int* cur     = (int*)d_ws + 260;
  int* hist    = (int*)d_ws + 260;
  int* rows    = (int*)d_ws + 516;

  hipMemsetAsync(hist, 0, NEXP * sizeof(int), stream);
  hist_k<<<NROWS / 256, 256, 0, stream>>>(ind, hist);
  scan_k<<<1, 256, 0, stream>>>(hist, offsets, cur);
  scatter_k<<<NROWS / 256, 256, 0, stream>>>(ind, cur, rows);
  mlp_k<<<NEXP, 512, 0, stream>>>(x, W1, b1, W2, b2, Wl, bl, rows, offsets, out);
}

// Round 4
// 163.456 us; speedup vs baseline: 1.0402x; 1.0058x over previous
//
#include <hip/hip_runtime.h>
#include <math.h>

#define NROWS   16384
#define IN_DIM  64
#define HID     256
#define OUT_DIM 64
#define NEXP    256
#define MT      112    // rows per tile (7 x 16); covers ~all experts in one pass
#define NT      7      // row tiles of 16
#define HP      264    // padded LDS row stride (bf16 elems): 528 B, 16B-aligned

typedef __attribute__((ext_vector_type(8))) short short8;   // 8 bf16 (4 VGPRs)
typedef __attribute__((ext_vector_type(4))) float f32x4;
typedef __attribute__((ext_vector_type(4))) unsigned uint4v;
typedef __attribute__((ext_vector_type(2))) unsigned uint2v;

// LDS-publish barrier: orders ds ops cross-wave WITHOUT draining vmcnt, so
// per-wave global weight loads stay in flight across layer boundaries
// (__syncthreads would emit s_waitcnt vmcnt(0) and kill the prefetch).
#define LBAR() do { \
    asm volatile("s_waitcnt lgkmcnt(0)" ::: "memory"); \
    __builtin_amdgcn_s_barrier(); } while (0)

// ---------------- parallel bucketing: memset + 3 small kernels ----------------

__global__ __launch_bounds__(256) void hist_k(const int* __restrict__ ind,
                                              int* __restrict__ hist) {
  int n = blockIdx.x * 256 + threadIdx.x;
  atomicAdd(&hist[ind[n]], 1);
}

__global__ __launch_bounds__(256) void scan_k(const int* __restrict__ hist,
                                              int* __restrict__ offsets,
                                              int* __restrict__ cur) {
  __shared__ int s[NEXP];
  int t = threadIdx.x;
  int h = hist[t];            // all reads complete before any write to cur/offsets
  s[t] = h;
  __syncthreads();
  for (int d = 1; d < NEXP; d <<= 1) {
    int v = (t >= d) ? s[t - d] : 0;
    __syncthreads();
    s[t] += v;
    __syncthreads();
  }
  int exc = s[t] - h;
  offsets[t] = exc;
  cur[t] = exc;
  if (t == NEXP - 1) offsets[NEXP] = s[t];
}

__global__ __launch_bounds__(256) void scatter_k(const int* __restrict__ ind,
                                                 int* __restrict__ cur,
                                                 int* __restrict__ rows) {
  int n = blockIdx.x * 256 + threadIdx.x;
  int p = atomicAdd(&cur[ind[n]], 1);
  rows[p] = n;
}

// ---------------- helpers ----------------

__device__ __forceinline__ unsigned bf16_rn(float f) {
  unsigned u = __builtin_bit_cast(unsigned, f);
  unsigned r = 0x7fffu + ((u >> 16) & 1u);
  return (u + r) >> 16;
}

__device__ __forceinline__ unsigned pk2(float a, float b) {
  return bf16_rn(a) | (bf16_rn(b) << 16);
}

__device__ __forceinline__ short8 cvt8(f32x4 w0, f32x4 w1) {
  uint4v u;
  u.x = pk2(w0.x, w0.y);
  u.y = pk2(w0.z, w0.w);
  u.z = pk2(w1.x, w1.y);
  u.w = pk2(w1.z, w1.w);
  return __builtin_bit_cast(short8, u);
}

__device__ __forceinline__ float fast_tanh(float v) {
  float e = __expf(2.f * v);
  return 1.f - 2.f * __builtin_amdgcn_rcpf(e + 1.f);
}

// ---------------- per-wave direct weight streaming layers ----------------
// Each wave owns 32 neurons (2 mt of 16). Weight fragments stream straight
// from global to VGPRs (never LDS): per lane, rows mt*16+l15, cols ks*32+q*8,
// as 2x f32x4 with compile-time offsets after unroll. No barriers inside.

__device__ __forceinline__ void preload2(const float* bp0, const float* bp1,
                                         f32x4 (&p)[2][2]) {
  p[0][0] = *(const f32x4*)(bp0);
  p[0][1] = *(const f32x4*)(bp0 + 4);
  p[1][0] = *(const f32x4*)(bp1);
  p[1][1] = *(const f32x4*)(bp1 + 4);
}

// layer1: K=64 (2 K-steps), depth-1 pipeline, ks0 preloaded by caller.
__device__ __forceinline__ void layer1_direct(const float* bp0, const float* bp1,
                                              f32x4 (&pre)[2][2],
                                              const unsigned short* Hin,
                                              int l15, int q, f32x4 (&acc)[2][NT]) {
  f32x4 wp[2][2][2];
  wp[0][0][0] = pre[0][0]; wp[0][0][1] = pre[0][1];
  wp[0][1][0] = pre[1][0]; wp[0][1][1] = pre[1][1];
#pragma unroll
  for (int ks = 0; ks < 2; ks++) {
    const int cu = ks & 1;
    if (ks + 1 < 2) {
      wp[cu ^ 1][0][0] = *(const f32x4*)(bp0 + (ks + 1) * 32);
      wp[cu ^ 1][0][1] = *(const f32x4*)(bp0 + (ks + 1) * 32 + 4);
      wp[cu ^ 1][1][0] = *(const f32x4*)(bp1 + (ks + 1) * 32);
      wp[cu ^ 1][1][1] = *(const f32x4*)(bp1 + (ks + 1) * 32 + 4);
    }
    short8 a0 = cvt8(wp[cu][0][0], wp[cu][0][1]);
    short8 a1 = cvt8(wp[cu][1][0], wp[cu][1][1]);
#pragma unroll
    for (int nt = 0; nt < NT; nt++) {
      short8 b = *(const short8*)&Hin[(nt * 16 + l15) * HP + ks * 32 + q * 8];
      acc[0][nt] = __builtin_amdgcn_mfma_f32_16x16x32_bf16(a0, b, acc[0][nt], 0, 0, 0);
      acc[1][nt] = __builtin_amdgcn_mfma_f32_16x16x32_bf16(a1, b, acc[1][nt], 0, 0, 0);
    }
  }
}

// layer2: K=256 (8 K-steps), depth-2 pipeline (3-buffer ring), ks0+ks1
// preloaded by caller (they fly across the h1 barriers).
__device__ __forceinline__ void layer2_direct(const float* bp0, const float* bp1,
                                              f32x4 (&pre)[2][2][2],
                                              const unsigned short* Hin,
                                              int l15, int q, f32x4 (&acc)[2][NT]) {
  f32x4 wp[3][2][2];
  wp[0][0][0] = pre[0][0][0]; wp[0][0][1] = pre[0][0][1];
  wp[0][1][0] = pre[0][1][0]; wp[0][1][1] = pre[0][1][1];
  wp[1][0][0] = pre[1][0][0]; wp[1][0][1] = pre[1][0][1];
  wp[1][1][0] = pre[1][1][0]; wp[1][1][1] = pre[1][1][1];
#pragma unroll
  for (int ks = 0; ks < 8; ks++) {
    const int cu = ks % 3;
    const int ld = (ks + 2) % 3;
    if (ks + 2 < 8) {
      wp[ld][0][0] = *(const f32x4*)(bp0 + (ks + 2) * 32);
      wp[ld][0][1] = *(const f32x4*)(bp0 + (ks + 2) * 32 + 4);
      wp[ld][1][0] = *(const f32x4*)(bp1 + (ks + 2) * 32);
      wp[ld][1][1] = *(const f32x4*)(bp1 + (ks + 2) * 32 + 4);
    }
    short8 a0 = cvt8(wp[cu][0][0], wp[cu][0][1]);
    short8 a1 = cvt8(wp[cu][1][0], wp[cu][1][1]);
#pragma unroll
    for (int nt = 0; nt < NT; nt++) {
      short8 b = *(const short8*)&Hin[(nt * 16 + l15) * HP + ks * 32 + q * 8];
      acc[0][nt] = __builtin_amdgcn_mfma_f32_16x16x32_bf16(a0, b, acc[0][nt], 0, 0, 0);
      acc[1][nt] = __builtin_amdgcn_mfma_f32_16x16x32_bf16(a1, b, acc[1][nt], 0, 0, 0);
    }
  }
}

// layer3: 64 neurons, K=256 (8 K-steps), depth-1. Wave w owns neurons
// (w&3)*16..+15; waves 0-3 cover row tiles 0..3, waves 4-7 cover 4..6.
__device__ __forceinline__ void layer3_direct(const float* bp, f32x4 (&pre)[2],
                                              const unsigned short* Hin,
                                              int w, int l15, int q,
                                              f32x4 (&accl)[4]) {
  f32x4 wp[2][2];
  wp[0][0] = pre[0]; wp[0][1] = pre[1];
#pragma unroll
  for (int kk = 0; kk < 8; kk++) {
    const int cu = kk & 1;
    if (kk + 1 < 8) {
      wp[cu ^ 1][0] = *(const f32x4*)(bp + (kk + 1) * 32);
      wp[cu ^ 1][1] = *(const f32x4*)(bp + (kk + 1) * 32 + 4);
    }
    short8 a = cvt8(wp[cu][0], wp[cu][1]);
#pragma unroll
    for (int i = 0; i < 4; i++) {
      int nt = (w >> 2) * 4 + i;
      if (nt < NT) {
        short8 b = *(const short8*)&Hin[(nt * 16 + l15) * HP + kk * 32 + q * 8];
        accl[i] = __builtin_amdgcn_mfma_f32_16x16x32_bf16(a, b, accl[i], 0, 0, 0);
      }
    }
  }
}

// tanh + pack + store h frags: frag (mt,nt) -> H[row nt*16+l15][neurons w*32+mt*16+q*4..+3]
__device__ __forceinline__ void write_h8(f32x4 (&acc)[2][NT], unsigned short* Hd,
                                         int w, int l15, int q) {
#pragma unroll
  for (int mt = 0; mt < 2; mt++)
#pragma unroll
    for (int nt = 0; nt < NT; nt++) {
      uint2v v;
      v.x = pk2(fast_tanh(acc[mt][nt].x), fast_tanh(acc[mt][nt].y));
      v.y = pk2(fast_tanh(acc[mt][nt].z), fast_tanh(acc[mt][nt].w));
      *(uint2v*)&Hd[(nt * 16 + l15) * HP + w * 32 + mt * 16 + q * 4] = v;
    }
}

// ---------------- main MLP kernel: 1 block/expert, per-wave weight streams ----
// LDS = H only (59136 B). Weights go global->VGPR, software-pipelined, with
// NO per-slice barriers: waves run decoupled, self-staggering memory demand
// (the mechanism that let R0 sustain 4.2 TB/s effective source rate).

__global__ __launch_bounds__(512, 2) void mlp_k(
    const float* __restrict__ x,
    const float* __restrict__ W1, const float* __restrict__ b1,
    const float* __restrict__ W2, const float* __restrict__ b2,
    const float* __restrict__ Wl, const float* __restrict__ bl,
    const int* __restrict__ rows, const int* __restrict__ offsets,
    float* __restrict__ out) {
  __shared__ __align__(16) unsigned short H[MT * HP];  // 59136 B

  const int t = threadIdx.x;
  const int w = t >> 6;          // wave 0..7
  const int l15 = t & 15;
  const int q = (t >> 4) & 3;
  const int e = blockIdx.x;
  const int beg = offsets[e];
  const int cnt = offsets[e + 1] - beg;

  const float* W1e = W1 + (size_t)e * HID * IN_DIM;
  const float* W2e = W2 + (size_t)e * HID * HID;
  const float* Wle = Wl + (size_t)e * OUT_DIM * HID;

  // per-lane weight base pointers (row = neuron, col base = q*8)
  const float* bp1a = W1e + (size_t)(w * 32 + l15) * IN_DIM + q * 8;
  const float* bp1b = W1e + (size_t)(w * 32 + 16 + l15) * IN_DIM + q * 8;
  const float* bp2a = W2e + (size_t)(w * 32 + l15) * HID + q * 8;
  const float* bp2b = W2e + (size_t)(w * 32 + 16 + l15) * HID + q * 8;
  const float* bp3  = Wle + (size_t)((w & 3) * 16 + l15) * HID + q * 8;

  f32x4 b1v[2], b2v[2], blv;
#pragma unroll
  for (int mt = 0; mt < 2; mt++) {
    b1v[mt] = *(const f32x4*)(b1 + (size_t)e * HID + w * 32 + mt * 16 + q * 4);
    b2v[mt] = *(const f32x4*)(b2 + (size_t)e * HID + w * 32 + mt * 16 + q * 4);
  }
  blv = *(const f32x4*)(bl + (size_t)e * OUT_DIM + (w & 3) * 16 + q * 4);

  const int sr = t >> 2;          // x-stage: row 0..127 (only 0..111 active)
  const int sc = (t & 3) * 16;    // x-stage: col base

  for (int mt0 = 0; mt0 < cnt; mt0 += MT) {
    // ---- prologue: issue first-K-step weight loads for ALL layers so they
    // fly across the early barriers, then gather+stage x.
    f32x4 p1[2][2], p2[2][2][2], p3[2];
    preload2(bp1a, bp1b, p1);
    preload2(bp2a, bp2b, p2[0]);
    preload2(bp2a + 32, bp2b + 32, p2[1]);
    p3[0] = *(const f32x4*)(bp3);
    p3[1] = *(const f32x4*)(bp3 + 4);

    if (sr < MT) {
      int gm = mt0 + sr;
      bool val = gm < cnt;
      int r = val ? rows[beg + gm] : 0;
      const float* xr = x + (size_t)r * IN_DIM + sc;
      uint4v u0, u1;
      if (val) {
        f32x4 a0 = *(const f32x4*)(xr);
        f32x4 a1 = *(const f32x4*)(xr + 4);
        f32x4 a2 = *(const f32x4*)(xr + 8);
        f32x4 a3 = *(const f32x4*)(xr + 12);
        u0.x = pk2(a0.x, a0.y); u0.y = pk2(a0.z, a0.w);
        u0.z = pk2(a1.x, a1.y); u0.w = pk2(a1.z, a1.w);
        u1.x = pk2(a2.x, a2.y); u1.y = pk2(a2.z, a2.w);
        u1.z = pk2(a3.x, a3.y); u1.w = pk2(a3.z, a3.w);
      } else {
        u0 = (uint4v){0, 0, 0, 0};
        u1 = (uint4v){0, 0, 0, 0};
      }
      *(uint4v*)&H[sr * HP + sc] = u0;
      *(uint4v*)&H[sr * HP + sc + 8] = u1;
    }
    LBAR();                                 // x visible to all waves

    // ---- layer1: x(K=64) -> h1(256), tanh
    f32x4 acc[2][NT];
#pragma unroll
    for (int mt = 0; mt < 2; mt++)
#pragma unroll
      for (int nt = 0; nt < NT; nt++) acc[mt][nt] = b1v[mt];
    layer1_direct(bp1a, bp1b, p1, H, l15, q, acc);
    LBAR();                                 // all x reads done
    write_h8(acc, H, w, l15, q);            // h1 (in place over x)
    LBAR();                                 // h1 visible

    // ---- layer2: h1(K=256) -> h2(256), tanh
#pragma unroll
    for (int mt = 0; mt < 2; mt++)
#pragma unroll
      for (int nt = 0; nt < NT; nt++) acc[mt][nt] = b2v[mt];
    layer2_direct(bp2a, bp2b, p2, H, l15, q, acc);
    LBAR();                                 // all h1 reads done
    write_h8(acc, H, w, l15, q);            // h2 (in place over h1)
    LBAR();                                 // h2 visible

    // ---- layer3: h2(K=256) -> out(64)
    f32x4 accl[4];
#pragma unroll
    for (int i = 0; i < 4; i++) accl[i] = blv;
    layer3_direct(bp3, p3, H, w, l15, q, accl);

#pragma unroll
    for (int i = 0; i < 4; i++) {
      int nt = (w >> 2) * 4 + i;
      if (nt < NT) {
        int gm = mt0 + nt * 16 + l15;
        if (gm < cnt) {
          int r = rows[beg + gm];
          *(f32x4*)(out + (size_t)r * OUT_DIM + (w & 3) * 16 + q * 4) = accl[i];
        }
      }
    }
    LBAR();  // protect H before next tile's x-stage (multi-tile case)
  }
}

// ---------------- launcher ----------------

extern "C" void kernel_launch(void* const* d_in, const int* in_sizes, int n_in,
                              void* d_out, int out_size, void* d_ws, size_t ws_size,
                              hipStream_t stream) {
  const float* x   = (const float*)d_in[0];
  const int*   ind = (const int*)d_in[1];
  const float* W1  = (const float*)d_in[2];
  const float* b1  = (const float*)d_in[3];
  const float* W2  = (const float*)d_in[4];
  const float* b2  = (const float*)d_in[5];
  const float* Wl  = (const float*)d_in[6];
  const float* bl  = (const float*)d_in[7];
  float* out = (float*)d_out;

  // ws layout (ints): offsets @0 (257) | hist/cur @260 (256) | rows @516 (16384)
  // hist and cur alias: scan_k reads all of hist before writing any of cur.
  int* offsets = (int*)d_ws;
  int* cur     = (int*)d_ws + 260;
  int* hist    = (int*)d_ws + 260;
  int* rows    = (int*)d_ws + 516;

  hipMemsetAsync(hist, 0, NEXP * sizeof(int), stream);
  hist_k<<<NROWS / 256, 256, 0, stream>>>(ind, hist);
  scan_k<<<1, 256, 0, stream>>>(hist, offsets, cur);
  scatter_k<<<NROWS / 256, 256, 0, stream>>>(ind, cur, rows);
  mlp_k<<<NEXP, 512, 0, stream>>>(x, W1, b1, W2, b2, Wl, bl, rows, offsets, out);
}